// Round 1
// baseline (930.242 us; speedup 1.0000x reference)
//
#include <hip/hip_runtime.h>
#include <stddef.h>

#define N_NODES 50000
#define N_EDGES 800000
#define NF 96
#define FE 64
#define DIN 256
#define DOUT 192
#define BN_EPS 1e-5f
#define NTILES (N_EDGES / 64)

typedef float f32x4 __attribute__((ext_vector_type(4)));
typedef short bf16x8 __attribute__((ext_vector_type(8)));

__device__ __forceinline__ unsigned short f2bf(float f) {
  unsigned int u = __float_as_uint(f);
  return (unsigned short)((u + 0x7fffu + ((u >> 16) & 1u)) >> 16);
}
__device__ __forceinline__ float sigmoidf_(float x) { return 1.f / (1.f + __expf(-x)); }
__device__ __forceinline__ float softplusf_(float x) {
  return fmaxf(x, 0.f) + log1pf(__expf(-fabsf(x)));
}

// ---------------- conversion kernels ----------------
__global__ void k_cvt(const float* __restrict__ in, unsigned short* __restrict__ out, int n4) {
  int stride = gridDim.x * blockDim.x;
  for (int i = blockIdx.x * blockDim.x + threadIdx.x; i < n4; i += stride) {
    float4 v = reinterpret_cast<const float4*>(in)[i];
    ushort4 o;
    o.x = f2bf(v.x); o.y = f2bf(v.y); o.z = f2bf(v.z); o.w = f2bf(v.w);
    reinterpret_cast<ushort4*>(out)[i] = o;
  }
}

// Wt[c][k] = bf16(W[k][c])  (192 x 256, K-contiguous rows for B fragments)
__global__ void k_cvt_w(const float* __restrict__ W, unsigned short* __restrict__ Wt) {
  int i = blockIdx.x * blockDim.x + threadIdx.x;
  if (i < DOUT * DIN) {
    int c = i / DIN, k = i % DIN;
    Wt[i] = f2bf(W[k * DOUT + c]);
  }
}

__global__ void k_hist(const int* __restrict__ idx1, float* __restrict__ counts) {
  int stride = gridDim.x * blockDim.x;
  for (int e = blockIdx.x * blockDim.x + threadIdx.x; e < N_EDGES; e += stride)
    atomicAdd(&counts[idx1[e]], 1.0f);
}

// ---------------- fused gather + GEMM ----------------
// tile = 64 edges x 192 cols, K=256 in two 128-halves restaged into LDS.
// A row e = [ nb[idx1[e]][0:96] | nb[idx2[e]][0:96] | eb[e][0:64] ] (bf16)
// PASS 0: column sum / sumsq of z=XW+b  (BN1 stats)
// PASS 1: zhat = XW*a1 + b1f ; msg = sigmoid(gate)*softplus(conv); atomic scatter by idx1
template <int PASS>
__global__ __launch_bounds__(256, 2) void k_gemm(
    const unsigned short* __restrict__ nb, const unsigned short* __restrict__ eb,
    const unsigned short* __restrict__ Wt, const int* __restrict__ idx1,
    const int* __restrict__ idx2, const float* __restrict__ cvec0,
    const float* __restrict__ cvec1, float* __restrict__ out1, float* __restrict__ out2) {
  __shared__ unsigned short As[64 * 128];   // 16 KB
  __shared__ unsigned short Ws[192 * 128];  // 48 KB
  __shared__ float colAcc[2][192];

  const int tid = threadIdx.x;
  const int lane = tid & 63;
  const int w = tid >> 6;      // wave id == row tile
  const int lm = lane & 15;
  const int hi = lane >> 4;

  if (PASS == 0) {
    for (int i = tid; i < 2 * 192; i += 256) ((float*)colAcc)[i] = 0.f;
  }

  // per-lane epilogue constants: PASS0: c0=b[col]; PASS1: c0=a1[col], c1=b1f[col]
  float c0[12], c1[12];
#pragma unroll
  for (int t = 0; t < 12; ++t) {
    c0[t] = cvec0[t * 16 + lm];
    c1[t] = (PASS == 1) ? cvec1[t * 16 + lm] : 0.f;
  }

  for (int tile = blockIdx.x; tile < NTILES; tile += gridDim.x) {
    const int e0 = tile * 64;
    f32x4 acc[12];
#pragma unroll
    for (int t = 0; t < 12; ++t) acc[t] = (f32x4)(0.f);

#pragma unroll
    for (int h2 = 0; h2 < 2; ++h2) {
      __syncthreads();  // previous LDS readers done
      // ---- stage A half (64 rows x 128 k, 16B chunks, XOR swizzle) ----
#pragma unroll
      for (int s = 0; s < 4; ++s) {
        int f = tid + s * 256;
        int r = f >> 4, c = f & 15;
        int e = e0 + r;
        const unsigned short* src;
        if (h2 == 0) {
          if (c < 12) src = nb + (size_t)idx1[e] * NF + c * 8;
          else        src = nb + (size_t)idx2[e] * NF + (c - 12) * 8;
        } else {
          if (c < 8)  src = nb + (size_t)idx2[e] * NF + 32 + c * 8;
          else        src = eb + (size_t)e * FE + (c - 8) * 8;
        }
        uint4 v = *reinterpret_cast<const uint4*>(src);
        *reinterpret_cast<uint4*>(&As[r * 128 + ((c ^ (r & 7)) * 8)]) = v;
      }
      // ---- stage W half (192 rows x 128 k) ----
#pragma unroll
      for (int s = 0; s < 12; ++s) {
        int f = tid + s * 256;
        int n = f >> 4, c = f & 15;
        uint4 v = *reinterpret_cast<const uint4*>(Wt + (size_t)n * DIN + h2 * 128 + c * 8);
        *reinterpret_cast<uint4*>(&Ws[n * 128 + ((c ^ (n & 7)) * 8)]) = v;
      }
      __syncthreads();
      // ---- 4 K-steps of 32 ----
#pragma unroll
      for (int ks = 0; ks < 4; ++ks) {
        const int r = w * 16 + lm;
        bf16x8 a = *reinterpret_cast<const bf16x8*>(
            &As[r * 128 + (((ks * 4 + hi) ^ (r & 7)) * 8)]);
#pragma unroll
        for (int t = 0; t < 12; ++t) {
          const int n = t * 16 + lm;
          bf16x8 bf = *reinterpret_cast<const bf16x8*>(
              &Ws[n * 128 + (((ks * 4 + hi) ^ (n & 7)) * 8)]);
          acc[t] = __builtin_amdgcn_mfma_f32_16x16x32_bf16(a, bf, acc[t], 0, 0, 0);
        }
      }
    }

    // ---- epilogue ----
    if (PASS == 0) {
#pragma unroll
      for (int t = 0; t < 12; ++t) {
        float s1 = 0.f, s2 = 0.f;
#pragma unroll
        for (int j = 0; j < 4; ++j) {
          float z = acc[t][j] + c0[t];
          s1 += z; s2 += z * z;
        }
        s1 += __shfl_xor(s1, 16); s2 += __shfl_xor(s2, 16);
        s1 += __shfl_xor(s1, 32); s2 += __shfl_xor(s2, 32);
        if (hi == 0) {
          atomicAdd(&colAcc[0][t * 16 + lm], s1);
          atomicAdd(&colAcc[1][t * 16 + lm], s2);
        }
      }
    } else {
      int eidx[4];
#pragma unroll
      for (int j = 0; j < 4; ++j) eidx[j] = idx1[e0 + w * 16 + hi * 4 + j];
#pragma unroll
      for (int t = 0; t < 6; ++t) {
#pragma unroll
        for (int j = 0; j < 4; ++j) {
          float zg = acc[t][j] * c0[t] + c1[t];
          float zc = acc[t + 6][j] * c0[t + 6] + c1[t + 6];
          float m = sigmoidf_(zg) * softplusf_(zc);
          atomicAdd(&out1[(size_t)eidx[j] * NF + t * 16 + lm], m);
        }
      }
    }
  }

  if (PASS == 0) {
    __syncthreads();
    for (int i = tid; i < 192; i += 256) {
      atomicAdd(&out1[i], colAcc[0][i]);
      atomicAdd(&out2[i], colAcc[1][i]);
    }
  }
}

// ---------------- BN affine computation ----------------
__global__ void k_bn1(const float* __restrict__ colsum, const float* __restrict__ colsumsq,
                      const float* __restrict__ b, const float* __restrict__ gamma1,
                      const float* __restrict__ beta1, float* __restrict__ a1,
                      float* __restrict__ b1f) {
  int c = threadIdx.x;  // 192
  float m = colsum[c] * (1.f / N_EDGES);
  float v = colsumsq[c] * (1.f / N_EDGES) - m * m;
  float a = gamma1[c] * rsqrtf(v + BN_EPS);
  a1[c] = a;
  b1f[c] = beta1[c] + (b[c] - m) * a;  // fold bias: zhat = XW*a1 + b1f
}

__global__ void k_nodestats(const float* __restrict__ sums, const float* __restrict__ counts,
                            float* __restrict__ colsum2, float* __restrict__ colsumsq2) {
  __shared__ float sh[2][2][96];
  int t = threadIdx.x;  // 192
  int c = t % 96, sub = t / 96;
  float s1 = 0.f, s2 = 0.f;
  int n0 = blockIdx.x * 256;
  for (int r = sub; r < 256; r += 2) {
    int n = n0 + r;
    if (n < N_NODES) {
      float v = sums[(size_t)n * NF + c] / fmaxf(counts[n], 1.f);
      s1 += v; s2 += v * v;
    }
  }
  sh[0][sub][c] = s1; sh[1][sub][c] = s2;
  __syncthreads();
  if (sub == 0) {
    atomicAdd(&colsum2[c], s1 + sh[0][1][c]);
    atomicAdd(&colsumsq2[c], s2 + sh[1][1][c]);
  }
}

__global__ void k_bn2(const float* __restrict__ colsum2, const float* __restrict__ colsumsq2,
                      const float* __restrict__ gamma2, const float* __restrict__ beta2,
                      float* __restrict__ a2, float* __restrict__ b2f) {
  int c = threadIdx.x;
  if (c < 96) {
    float m = colsum2[c] * (1.f / N_NODES);
    float v = colsumsq2[c] * (1.f / N_NODES) - m * m;
    float a = gamma2[c] * rsqrtf(v + BN_EPS);
    a2[c] = a;
    b2f[c] = beta2[c] - m * a;
  }
}

__global__ void k_final(const float* __restrict__ node, const float* __restrict__ sums,
                        const float* __restrict__ counts, const float* __restrict__ a2,
                        const float* __restrict__ b2f, float* __restrict__ out) {
  int stride = gridDim.x * blockDim.x;
  for (int i = blockIdx.x * blockDim.x + threadIdx.x; i < N_NODES * NF / 4; i += stride) {
    int n = i / 24, c4 = (i % 24) * 4;
    float inv = 1.f / fmaxf(counts[n], 1.f);
    float4 s = reinterpret_cast<const float4*>(sums)[i];
    float4 nf = reinterpret_cast<const float4*>(node)[i];
    float4 o;
    o.x = softplusf_(nf.x + s.x * inv * a2[c4 + 0] + b2f[c4 + 0]);
    o.y = softplusf_(nf.y + s.y * inv * a2[c4 + 1] + b2f[c4 + 1]);
    o.z = softplusf_(nf.z + s.z * inv * a2[c4 + 2] + b2f[c4 + 2]);
    o.w = softplusf_(nf.w + s.w * inv * a2[c4 + 3] + b2f[c4 + 3]);
    reinterpret_cast<float4*>(out)[i] = o;
  }
}

extern "C" void kernel_launch(void* const* d_in, const int* in_sizes, int n_in,
                              void* d_out, int out_size, void* d_ws, size_t ws_size,
                              hipStream_t stream) {
  const float* node = (const float*)d_in[0];
  const float* edge = (const float*)d_in[1];
  const float* W = (const float*)d_in[2];
  const float* b = (const float*)d_in[3];
  const float* gamma1 = (const float*)d_in[4];
  const float* beta1 = (const float*)d_in[5];
  const float* gamma2 = (const float*)d_in[6];
  const float* beta2 = (const float*)d_in[7];
  const int* idx1 = (const int*)d_in[8];
  const int* idx2 = (const int*)d_in[9];
  float* out = (float*)d_out;

  char* ws = (char*)d_ws;
  // workspace layout (bytes)
  unsigned short* nb = (unsigned short*)(ws);                    //  9,600,000
  unsigned short* eb = (unsigned short*)(ws + 9600000);          // 102,400,000
  unsigned short* Wt = (unsigned short*)(ws + 112000000);        //      98,304
  float* sums  = (float*)(ws + 112098304);                       //  19,200,000
  float* counts = (float*)(ws + 131298304);                      //     200,000
  float* stats = (float*)(ws + 131498304);                       //       4,608
  float* colsum1 = stats;          // 192
  float* colsumsq1 = stats + 192;  // 192
  float* colsum2 = stats + 384;    // 96
  float* colsumsq2 = stats + 480;  // 96
  float* a1 = stats + 576;         // 192
  float* b1f = stats + 768;        // 192
  float* a2 = stats + 960;         // 96
  float* b2f = stats + 1056;       // 96

  // zero accumulators (sums + counts + stats, contiguous)
  hipMemsetAsync(ws + 112098304, 0, 19200000 + 200000 + 4608, stream);

  k_cvt<<<2048, 256, 0, stream>>>(node, nb, N_NODES * NF / 4);
  k_cvt<<<2048, 256, 0, stream>>>(edge, eb, N_EDGES * FE / 4);
  k_cvt_w<<<DOUT * DIN / 256, 256, 0, stream>>>(W, Wt);
  k_hist<<<1024, 256, 0, stream>>>(idx1, counts);

  k_gemm<0><<<2048, 256, 0, stream>>>(nb, eb, Wt, idx1, idx2, b, nullptr,
                                      colsum1, colsumsq1);
  k_bn1<<<1, 192, 0, stream>>>(colsum1, colsumsq1, b, gamma1, beta1, a1, b1f);
  k_gemm<1><<<2048, 256, 0, stream>>>(nb, eb, Wt, idx1, idx2, a1, b1f, sums, nullptr);

  k_nodestats<<<(N_NODES + 255) / 256, 192, 0, stream>>>(sums, counts, colsum2, colsumsq2);
  k_bn2<<<1, 128, 0, stream>>>(colsum2, colsumsq2, gamma2, beta2, a2, b2f);
  k_final<<<2048, 256, 0, stream>>>(node, sums, counts, a2, b2f, out);
}